// Round 3
// baseline (323.461 us; speedup 1.0000x reference)
//
#include <hip/hip_runtime.h>

// Problem constants (from reference)
#define BATCH 32
#define NB    64
#define CH    8
#define CORE  32
#define RES   64
#define POS   16                          // (RES-CORE)/2
#define DIM   (CORE*CORE*CORE*CH)         // 262144
#define OUT_PER_B (CH*RES*RES*RES)        // 2097152

#define DPT   2                                       // d's per core thread
#define CORE_BLOCKS (DIM/(256*DPT))                   // 512

// zero side: 16,777,216 float4 slots total; 4 slots per thread
#define TOTAL_F4   (BATCH * OUT_PER_B / 4)            // 16777216
#define ZPT        4                                  // float4 stores per thread
#define ZTHREADS   (TOTAL_F4 / ZPT)                   // 4194304
#define ZERO_BLOCKS (ZTHREADS / 256)                  // 16384

typedef float vfloat4 __attribute__((ext_vector_type(4)));

// Fused kernel:
//  blocks [0, CORE_BLOCKS): compute core GEMM (st staged in LDS), write placed
//  blocks [CORE_BLOCKS, ...): grid-stride periphery zeroing, 4 float4/thread,
//                             nontemporal (exact partition with the core)
__global__ __launch_bounds__(256) void core_part_kernel(
        const float* __restrict__ U,
        const float* __restrict__ mu,
        const float* __restrict__ z,
        const float* __restrict__ L,
        float* __restrict__ out) {
    const int bid = blockIdx.x;
    const int tid = threadIdx.x;
    if (bid < CORE_BLOCKS) {
        // ---- stage st[k*32+b] = z[b,k]*L[k] into LDS (8 KB)
        __shared__ float st[NB * BATCH];
#pragma unroll
        for (int r = 0; r < 8; ++r) {
            const int idx = r * 256 + tid;   // idx = k*32 + b
            const int k = idx >> 5;
            const int b = idx & 31;
            st[idx] = z[b * NB + k] * L[k];
        }
        __syncthreads();

        // ---- core GEMM: out[b, place(d)] = sum_k st[k][b] * U[k][d] + mu[d]
        const int d0 = (bid * 256 + tid) * DPT;   // two consecutive d's
        float acc0[BATCH], acc1[BATCH];
#pragma unroll
        for (int b = 0; b < BATCH; ++b) { acc0[b] = 0.f; acc1[b] = 0.f; }

#pragma unroll 2
        for (int k = 0; k < NB; ++k) {
            const float2 u = *(const float2*)&U[(size_t)k * DIM + d0]; // coalesced
#pragma unroll
            for (int q = 0; q < 8; ++q) {
                // wave-uniform LDS address -> broadcast, conflict-free
                const float4 s = *(const float4*)&st[k * BATCH + q * 4];
                acc0[q*4+0] += s.x * u.x;  acc1[q*4+0] += s.x * u.y;
                acc0[q*4+1] += s.y * u.x;  acc1[q*4+1] += s.y * u.y;
                acc0[q*4+2] += s.z * u.x;  acc1[q*4+2] += s.z * u.y;
                acc0[q*4+3] += s.w * u.x;  acc1[q*4+3] += s.w * u.y;
            }
        }

        const float2 m = *(const float2*)&mu[d0];
        // d0 -> (c, i, j, kk) in 8x32x32x32 ; d0 even so d0,d0+1 share a row
        const int c  = d0 >> 15;
        const int i  = (d0 >> 10) & 31;
        const int j  = (d0 >> 5) & 31;
        const int kk = d0 & 31;
        const size_t o = (size_t)c * (RES * RES * RES)
                       + (size_t)(i + POS) * (RES * RES)
                       + (size_t)(j + POS) * RES
                       + (size_t)(kk + POS);
#pragma unroll
        for (int b = 0; b < BATCH; ++b) {
            float2 v = make_float2(acc0[b] + m.x, acc1[b] + m.y);
            *(float2*)&out[(size_t)b * OUT_PER_B + o] = v;   // 8B-aligned
        }
    } else {
        // ---- periphery zeroing: 4 grid-strided float4 stores per thread;
        // skip slots inside the core (exact partition: core == i,j in [16,48),
        // float4-group g in [4,12) within the row).
        const size_t t = (size_t)(bid - CORE_BLOCKS) * 256 + tid;
        vfloat4* o4 = (vfloat4*)out;
        const vfloat4 zero4 = {0.f, 0.f, 0.f, 0.f};
#pragma unroll
        for (int it = 0; it < ZPT; ++it) {
            const size_t slot = t + (size_t)it * ZTHREADS;
            const int rem = (int)(slot & 65535);   // within one (b,c) 64^3/4 chunk
            const int i = rem >> 10;
            const int j = (rem >> 4) & 63;
            const int g = rem & 15;
            const bool in_core = (i >= POS) & (i < POS + CORE) &
                                 (j >= POS) & (j < POS + CORE) &
                                 (g >= 4) & (g < 12);
            if (!in_core) {
                __builtin_nontemporal_store(zero4, &o4[slot]);
            }
        }
    }
}

extern "C" void kernel_launch(void* const* d_in, const int* in_sizes, int n_in,
                              void* d_out, int out_size, void* d_ws, size_t ws_size,
                              hipStream_t stream) {
    const float* z  = (const float*)d_in[0];   // (32, 64)
    const float* U  = (const float*)d_in[1];   // (64, 262144)
    const float* L  = (const float*)d_in[2];   // (64,)
    const float* mu = (const float*)d_in[3];   // (262144,)
    float* out = (float*)d_out;                // (32, 8, 64, 64, 64)

    core_part_kernel<<<CORE_BLOCKS + ZERO_BLOCKS, 256, 0, stream>>>(U, mu, z, L, out);
}